// Round 1
// baseline (647.935 us; speedup 1.0000x reference)
//
#include <hip/hip_runtime.h>
#include <math.h>

#define B_TOT   16384
#define SB      5
#define TPB     256
#define SSTRIDE 2972
#define OFF_X   0
#define OFF_H   44
#define OFF_H1  440
#define OFF_EA  836
#define OFF_M   904
#define OFF_AGG 1516
#define OFF_TD  OFF_AGG
#define OFF_TS  (OFF_AGG + 396)
#define AVG_LOG 0.9976091242438673f

// Fixed replicated DAG (from _BASE_EDGES)
__constant__ int   C_ESRC[17] = {0,0,1,1,2,0,3,4,5,6,7,2,8,3,6,9,1};
__constant__ int   C_EDST[17] = {3,4,3,5,5,6,6,7,7,8,8,9,9,10,10,10,10};
__constant__ int   C_INS[12]  = {0,0,0,0,2,3,5,7,9,11,13,17};
__constant__ int   C_INE[17]  = {0,2,1,3,4,5,6,7,8,9,10,11,12,13,14,15,16};
__constant__ float C_CNTC[11] = {1.f,1.f,1.f,2.f,1.f,2.f,2.f,2.f,2.f,2.f,4.f};

// ---- per-node transform of the edge pre-MLP: T[n][f] = H[n] @ Wpre[part] (+bias for dst part)
// wave mapping: ty = w&1 (0: dst rows 0..31 (+bias), 1: src rows 32..63), f0 = (w>>1)*16
static __device__ __forceinline__ void conv_T(float* lds, int nsamp, int w, int lane, int hoff,
                                              const float* __restrict__ Wp,
                                              const float* __restrict__ bp)
{
    const int ty = w & 1;
    const int f0 = (w >> 1) * 16;
    const int idx = lane;                       // tasks = nsamp*11 <= 55
    const bool act = idx < nsamp * 11;
    const int cidx = act ? idx : 0;
    const int s = cidx / 11, n = cidx % 11;
    const float* Hrow = lds + s * SSTRIDE + hoff + n * 36;
    const float* wbase = Wp + ty * 32 * 32 + f0;   // uniform
    float acc[16];
#pragma unroll
    for (int f = 0; f < 16; f++) acc[f] = ty ? 0.f : bp[f0 + f];
#pragma unroll
    for (int kq = 0; kq < 8; kq++) {
        float4 a = *(const float4*)(Hrow + kq * 4);
#pragma unroll
        for (int kk = 0; kk < 4; kk++) {
            float av = (kk == 0) ? a.x : (kk == 1) ? a.y : (kk == 2) ? a.z : a.w;
            const float* wr = wbase + (kq * 4 + kk) * 32;   // uniform -> s_load
#pragma unroll
            for (int f = 0; f < 16; f++) acc[f] = fmaf(av, wr[f], acc[f]);
        }
    }
    float* T = lds + s * SSTRIDE + (ty ? OFF_TS : OFF_TD) + n * 36 + f0;
    if (act) {
#pragma unroll
        for (int fq = 0; fq < 4; fq++)
            *(float4*)(T + fq * 4) = make_float4(acc[fq*4], acc[fq*4+1], acc[fq*4+2], acc[fq*4+3]);
    }
}

// ---- combine: m[e][f] = relu(Td[dst] + Ts[src] + ea@Wpre[64:68])
// wave mapping: half = w&1 (f0 = half*16), v = w>>1 ; idx = v*64+lane over nsamp*17 <= 85
static __device__ __forceinline__ void conv_combine(float* lds, int nsamp, int w, int lane,
                                                    const float* __restrict__ Wp)
{
    const int half = w & 1, v = w >> 1;
    const int f0 = half * 16;
    const int idx = v * 64 + lane;
    const bool act = idx < nsamp * 17;
    const int cidx = act ? idx : 0;
    const int s = cidx / 17, e = cidx % 17;
    float* S = lds + s * SSTRIDE;
    const int nd = C_EDST[e], ns = C_ESRC[e];
    float4 ev = *(const float4*)(S + OFF_EA + e * 4);
    const float* TD = S + OFF_TD + nd * 36 + f0;
    const float* TS = S + OFF_TS + ns * 36 + f0;
    float acc[16];
#pragma unroll
    for (int fq = 0; fq < 4; fq++) {
        float4 td = *(const float4*)(TD + fq * 4);
        float4 ts = *(const float4*)(TS + fq * 4);
        acc[fq*4+0] = td.x + ts.x; acc[fq*4+1] = td.y + ts.y;
        acc[fq*4+2] = td.z + ts.z; acc[fq*4+3] = td.w + ts.w;
    }
    const float* w64 = Wp + 64 * 32 + f0;   // uniform rows
    const float* w65 = Wp + 65 * 32 + f0;
    const float* w66 = Wp + 66 * 32 + f0;
    const float* w67 = Wp + 67 * 32 + f0;
#pragma unroll
    for (int f = 0; f < 16; f++) {
        float a = acc[f];
        a = fmaf(ev.x, w64[f], a);
        a = fmaf(ev.y, w65[f], a);
        a = fmaf(ev.z, w66[f], a);
        a = fmaf(ev.w, w67[f], a);
        acc[f] = fmaxf(a, 0.f);
    }
    float* M = S + OFF_M + e * 36 + f0;
    if (act) {
#pragma unroll
        for (int fq = 0; fq < 4; fq++)
            *(float4*)(M + fq * 4) = make_float4(acc[fq*4], acc[fq*4+1], acc[fq*4+2], acc[fq*4+3]);
    }
}

// ---- PNA aggregation into agg[n][128] = [mean | mn | mx | std]
static __device__ __forceinline__ void agg_phase(float* lds, int nsamp, int tid)
{
    for (int t = tid; t < nsamp * 88; t += TPB) {
        const int s = t / 88, r = t % 88, n = r >> 3, f = (r & 7) * 4;
        float* S = lds + s * SSTRIDE;
        const int e0 = C_INS[n], e1 = C_INS[n + 1];
        float4 sum = make_float4(0.f,0.f,0.f,0.f), sq = make_float4(0.f,0.f,0.f,0.f);
        float4 mn = make_float4(1e30f,1e30f,1e30f,1e30f), mx = make_float4(-1e30f,-1e30f,-1e30f,-1e30f);
        for (int t2 = e0; t2 < e1; t2++) {
            const int e = C_INE[t2];
            float4 mv = *(const float4*)(S + OFF_M + e * 36 + f);
            sum.x += mv.x; sum.y += mv.y; sum.z += mv.z; sum.w += mv.w;
            sq.x = fmaf(mv.x, mv.x, sq.x); sq.y = fmaf(mv.y, mv.y, sq.y);
            sq.z = fmaf(mv.z, mv.z, sq.z); sq.w = fmaf(mv.w, mv.w, sq.w);
            mn.x = fminf(mn.x, mv.x); mn.y = fminf(mn.y, mv.y); mn.z = fminf(mn.z, mv.z); mn.w = fminf(mn.w, mv.w);
            mx.x = fmaxf(mx.x, mv.x); mx.y = fmaxf(mx.y, mv.y); mx.z = fmaxf(mx.z, mv.z); mx.w = fmaxf(mx.w, mv.w);
        }
        const float inv = 1.f / C_CNTC[n];      // cnt_c in {1,2,4}: exact
        float4 mean = make_float4(sum.x*inv, sum.y*inv, sum.z*inv, sum.w*inv);
        float4 msq  = make_float4(sq.x*inv,  sq.y*inv,  sq.z*inv,  sq.w*inv);
        float4 sd;
        sd.x = sqrtf(fmaxf(msq.x - mean.x*mean.x, 0.f) + 1e-5f);
        sd.y = sqrtf(fmaxf(msq.y - mean.y*mean.y, 0.f) + 1e-5f);
        sd.z = sqrtf(fmaxf(msq.z - mean.z*mean.z, 0.f) + 1e-5f);
        sd.w = sqrtf(fmaxf(msq.w - mean.w*mean.w, 0.f) + 1e-5f);
        if (e0 == e1) { mn = make_float4(0.f,0.f,0.f,0.f); mx = make_float4(0.f,0.f,0.f,0.f); }
        float* A = S + OFF_AGG + n * 132;
        *(float4*)(A + 0  + f) = mean;
        *(float4*)(A + 32 + f) = mn;
        *(float4*)(A + 64 + f) = mx;
        *(float4*)(A + 96 + f) = sd;
    }
}

// ---- post1: h1[n][f] = relu(u0 + amp*u1 + att*u2 + b);  wave: f0 = w*8, idx = lane over nsamp*11
static __device__ __forceinline__ void post1_phase(float* lds, int nsamp, int w, int lane,
                                                   const float* __restrict__ Wp,
                                                   const float* __restrict__ bp)
{
    const int f0 = w * 8;
    const int idx = lane;
    const bool act = idx < nsamp * 11;
    const int cidx = act ? idx : 0;
    const int s = cidx / 11, n = cidx % 11;
    const float* A = lds + s * SSTRIDE + OFF_AGG + n * 132;
    const float* W0 = Wp + f0;                  // uniform bases
    const float* W1 = Wp + 128 * 32 + f0;
    const float* W2 = Wp + 256 * 32 + f0;
    float u0[8], u1[8], u2[8];
#pragma unroll
    for (int f = 0; f < 8; f++) { u0[f] = 0.f; u1[f] = 0.f; u2[f] = 0.f; }
    for (int jq = 0; jq < 32; jq++) {
        float4 a4 = *(const float4*)(A + jq * 4);
#pragma unroll
        for (int jj = 0; jj < 4; jj++) {
            float a = (jj == 0) ? a4.x : (jj == 1) ? a4.y : (jj == 2) ? a4.z : a4.w;
            const int j = jq * 4 + jj;
            const float* w0 = W0 + j * 32;
            const float* w1 = W1 + j * 32;
            const float* w2 = W2 + j * 32;
#pragma unroll
            for (int f = 0; f < 8; f++) {
                u0[f] = fmaf(a, w0[f], u0[f]);
                u1[f] = fmaf(a, w1[f], u1[f]);
                u2[f] = fmaf(a, w2[f], u2[f]);
            }
        }
    }
    const float logd = log1pf(C_CNTC[n]);
    const float amp = logd / AVG_LOG;
    const float att = AVG_LOG / logd;
    float* H1 = lds + s * SSTRIDE + OFF_H1 + n * 36 + f0;
    if (act) {
        float o[8];
#pragma unroll
        for (int f = 0; f < 8; f++) {
            float x = u0[f] + amp * u1[f] + att * u2[f] + bp[f0 + f];
            o[f] = fmaxf(x, 0.f);
        }
        *(float4*)(H1 + 0) = make_float4(o[0], o[1], o[2], o[3]);
        *(float4*)(H1 + 4) = make_float4(o[4], o[5], o[6], o[7]);
    }
}

// ---- post2 (+sigmoid + per-block accumulation into pacc[11])
static __device__ __forceinline__ void post2_phase(float* lds, int nsamp, int tid,
                                                   const float* __restrict__ Wp,
                                                   const float* __restrict__ bp, float* pacc)
{
    const int idx = tid;
    const bool act = idx < nsamp * 11;
    const int cidx = act ? idx : 0;
    const int s = cidx / 11, n = cidx % 11;
    const float* A = lds + s * SSTRIDE + OFF_AGG + n * 132;
    float u0 = 0.f, u1 = 0.f, u2 = 0.f;
    for (int jq = 0; jq < 32; jq++) {
        float4 a4 = *(const float4*)(A + jq * 4);
#pragma unroll
        for (int jj = 0; jj < 4; jj++) {
            float a = (jj == 0) ? a4.x : (jj == 1) ? a4.y : (jj == 2) ? a4.z : a4.w;
            const int j = jq * 4 + jj;
            u0 = fmaf(a, Wp[j], u0);
            u1 = fmaf(a, Wp[128 + j], u1);
            u2 = fmaf(a, Wp[256 + j], u2);
        }
    }
    const float logd = log1pf(C_CNTC[n]);
    const float amp = logd / AVG_LOG;
    const float att = AVG_LOG / logd;
    const float h2 = u0 + amp * u1 + att * u2 + bp[0];
    const float p = 1.f / (1.f + expf(-h2));
    if (act) atomicAdd(pacc + n, p);
}

extern "C" __global__ void __launch_bounds__(TPB, 2)
pna_main(const float* __restrict__ x_input, const float* __restrict__ edge_attr,
         const float* __restrict__ W_emb,  const float* __restrict__ b_emb,
         const float* __restrict__ W_pre1, const float* __restrict__ b_pre1,
         const float* __restrict__ W_post1,const float* __restrict__ b_post1,
         const float* __restrict__ W_pre2, const float* __restrict__ b_pre2,
         const float* __restrict__ W_post2,const float* __restrict__ b_post2,
         float* __restrict__ gacc)
{
    extern __shared__ float lds[];
    const int tid = threadIdx.x;
    const int w = __builtin_amdgcn_readfirstlane(tid >> 6);   // wave id, uniform
    const int lane = tid & 63;
    const int s0 = blockIdx.x * SB;
    const int nsamp = min(SB, B_TOT - s0);

    for (int t = tid; t < nsamp * 44; t += TPB)
        lds[(t / 44) * SSTRIDE + OFF_X + (t % 44)] = x_input[(size_t)s0 * 44 + t];
    for (int t = tid; t < nsamp * 68; t += TPB)
        lds[(t / 68) * SSTRIDE + OFF_EA + (t % 68)] = edge_attr[(size_t)s0 * 68 + t];
    __syncthreads();

    // embed: H[n][f] = relu(X[n] @ W_emb[n] + b_emb[n])
    for (int t = tid; t < nsamp * 352; t += TPB) {
        const int s = t / 352, r = t % 352, n = r >> 5, f = r & 31;
        const float* Xs = lds + s * SSTRIDE + OFF_X + n * 4;
        const float* We = W_emb + (n * 4) * 32 + f;
        float v = b_emb[n * 32 + f];
        v = fmaf(Xs[0], We[0],  v);
        v = fmaf(Xs[1], We[32], v);
        v = fmaf(Xs[2], We[64], v);
        v = fmaf(Xs[3], We[96], v);
        lds[s * SSTRIDE + OFF_H + n * 36 + f] = fmaxf(v, 0.f);
    }
    __syncthreads();

    float* pacc = lds + SB * SSTRIDE;

    for (int i = 0; i < 3; i++) {
        if (tid < 11) pacc[tid] = 0.f;
        // conv1
        conv_T(lds, nsamp, w, lane, OFF_H, W_pre1 + i * 68 * 32, b_pre1 + i * 32);
        __syncthreads();
        conv_combine(lds, nsamp, w, lane, W_pre1 + i * 68 * 32);
        __syncthreads();
        agg_phase(lds, nsamp, tid);
        __syncthreads();
        post1_phase(lds, nsamp, w, lane, W_post1 + i * 384 * 32, b_post1 + i * 32);
        __syncthreads();
        // conv2
        conv_T(lds, nsamp, w, lane, OFF_H1, W_pre2 + i * 68 * 32, b_pre2 + i * 32);
        __syncthreads();
        conv_combine(lds, nsamp, w, lane, W_pre2 + i * 68 * 32);
        __syncthreads();
        agg_phase(lds, nsamp, tid);
        __syncthreads();
        post2_phase(lds, nsamp, tid, W_post2 + i * 384, b_post2 + i, pacc);
        __syncthreads();
        if (tid < 11) atomicAdd(gacc + i * 11 + tid, pacc[tid]);
        __syncthreads();
    }
}

extern "C" __global__ void pna_zero(float* gacc)
{
    if (threadIdx.x < 33) gacc[threadIdx.x] = 0.f;
}

extern "C" __global__ void pna_final(const float* __restrict__ gacc,
                                     const float* __restrict__ W_fc,
                                     const float* __restrict__ b_fc,
                                     float* __restrict__ out)
{
    const int i = threadIdx.x;
    if (i < 3) {
        float acc = 0.f;
        for (int n = 0; n < 11; n++)
            acc = fmaf(gacc[i * 11 + n] * (1.f / 16384.f), W_fc[i * 11 + n], acc);
        out[i] = acc + b_fc[i];
    }
}

extern "C" void kernel_launch(void* const* d_in, const int* in_sizes, int n_in,
                              void* d_out, int out_size, void* d_ws, size_t ws_size,
                              hipStream_t stream)
{
    (void)in_sizes; (void)n_in; (void)out_size; (void)ws_size;
    const float* x_input   = (const float*)d_in[0];
    const float* edge_attr = (const float*)d_in[1];
    const float* W_emb     = (const float*)d_in[2];
    const float* b_emb     = (const float*)d_in[3];
    const float* W_pre1    = (const float*)d_in[4];
    const float* b_pre1    = (const float*)d_in[5];
    const float* W_post1   = (const float*)d_in[6];
    const float* b_post1   = (const float*)d_in[7];
    const float* W_pre2    = (const float*)d_in[8];
    const float* b_pre2    = (const float*)d_in[9];
    const float* W_post2   = (const float*)d_in[10];
    const float* b_post2   = (const float*)d_in[11];
    const float* W_fc      = (const float*)d_in[12];
    const float* b_fc      = (const float*)d_in[13];
    float* gacc = (float*)d_ws;
    float* out  = (float*)d_out;

    hipLaunchKernelGGL(pna_zero, dim3(1), dim3(64), 0, stream, gacc);
    const int grid = (B_TOT + SB - 1) / SB;
    const size_t shmem = (size_t)(SB * SSTRIDE + 16) * sizeof(float);
    hipLaunchKernelGGL(pna_main, dim3(grid), dim3(TPB), shmem, stream,
                       x_input, edge_attr, W_emb, b_emb,
                       W_pre1, b_pre1, W_post1, b_post1,
                       W_pre2, b_pre2, W_post2, b_post2, gacc);
    hipLaunchKernelGGL(pna_final, dim3(1), dim3(64), 0, stream, gacc, W_fc, b_fc, out);
}

// Round 2
// 433.673 us; speedup vs baseline: 1.4941x; 1.4941x over previous
//
#include <hip/hip_runtime.h>
#include <math.h>

#define B_TOT   16384
#define SB      5
#define TPB     512
#define SSTRIDE 2540          // %32 == 12: post1 AGG reads at most 2-way bank-aliased (free)
#define OFF_H   0             // 11*36 = 396
#define OFF_EA  396           // 68
#define OFF_M   464           // 17*36 = 612
#define OFF_H1  OFF_M         // aliased: H1 live only between post1 and conv_T2; M dead there
#define OFF_AGG 1076          // 11*132 = 1452
#define OFF_TD  OFF_AGG       // TD/TS alias AGG region (792 <= 1452)
#define OFF_TS  (OFF_AGG + 396)
#define OFF_PACC (SB*SSTRIDE)         // 16 floats
#define OFF_PP   (SB*SSTRIDE + 16)    // 8 waves * 55 tasks = 440 floats
#define LDS_FLOATS (SB*SSTRIDE + 16 + 440)
#define AVG_LOG 0.9976091242438673f

__constant__ int   C_ESRC[17] = {0,0,1,1,2,0,3,4,5,6,7,2,8,3,6,9,1};
__constant__ int   C_EDST[17] = {3,4,3,5,5,6,6,7,7,8,8,9,9,10,10,10,10};
__constant__ int   C_INS[12]  = {0,0,0,0,2,3,5,7,9,11,13,17};
__constant__ int   C_INE[17]  = {0,2,1,3,4,5,6,7,8,9,10,11,12,13,14,15,16};
__constant__ float C_CNTC[11] = {1.f,1.f,1.f,2.f,1.f,2.f,2.f,2.f,2.f,2.f,4.f};

// ---- per-node transform: T[n][f-octet] = H[n] @ Wpre[ty-part] (+bias for dst part)
// wave map: ty = w&1 (0: rows 0..31 +bias, 1: rows 32..63), f0 = (w>>1)*8
static __device__ __forceinline__ void conv_T(float* lds, int nsamp, int w, int lane, int hoff,
                                              const float* __restrict__ Wp,
                                              const float* __restrict__ bp)
{
    const int ty = w & 1;
    const int f0 = (w >> 1) * 8;
    const bool act = lane < nsamp * 11;
    const int cidx = act ? lane : 0;
    const int s = cidx / 11, n = cidx % 11;
    const float* Hrow = lds + s * SSTRIDE + hoff + n * 36;
    const float* wbase = Wp + ty * 32 * 32 + f0;        // wave-uniform -> s_load
    float acc[8];
#pragma unroll
    for (int f = 0; f < 8; f++) acc[f] = ty ? 0.f : bp[f0 + f];
#pragma unroll
    for (int kq = 0; kq < 8; kq++) {
        float4 a = *(const float4*)(Hrow + kq * 4);
#pragma unroll
        for (int kk = 0; kk < 4; kk++) {
            float av = (kk == 0) ? a.x : (kk == 1) ? a.y : (kk == 2) ? a.z : a.w;
            const float* wr = wbase + (kq * 4 + kk) * 32;
#pragma unroll
            for (int f = 0; f < 8; f++) acc[f] = fmaf(av, wr[f], acc[f]);
        }
    }
    float* T = lds + s * SSTRIDE + (ty ? OFF_TS : OFF_TD) + n * 36 + f0;
    if (act) {
        *(float4*)(T + 0) = make_float4(acc[0], acc[1], acc[2], acc[3]);
        *(float4*)(T + 4) = make_float4(acc[4], acc[5], acc[6], acc[7]);
    }
}

// ---- combine: m[e][f-octet] = relu(Td[dst] + Ts[src] + ea @ Wpre[64:68])
// wave map: f0 = (w&3)*8, v = w>>2; idx = v*64+lane over nsamp*17 (<=85)
static __device__ __forceinline__ void conv_combine(float* lds, int nsamp, int w, int lane,
                                                    const float* __restrict__ Wp)
{
    const int f0 = (w & 3) * 8, v = w >> 2;
    const int idx = v * 64 + lane;
    const bool act = idx < nsamp * 17;
    const int cidx = act ? idx : 0;
    const int s = cidx / 17, e = cidx % 17;
    float* S = lds + s * SSTRIDE;
    const int nd = C_EDST[e], ns = C_ESRC[e];
    float4 ev = *(const float4*)(S + OFF_EA + e * 4);
    const float* TD = S + OFF_TD + nd * 36 + f0;
    const float* TS = S + OFF_TS + ns * 36 + f0;
    float acc[8];
#pragma unroll
    for (int fq = 0; fq < 2; fq++) {
        float4 td = *(const float4*)(TD + fq * 4);
        float4 ts = *(const float4*)(TS + fq * 4);
        acc[fq*4+0] = td.x + ts.x; acc[fq*4+1] = td.y + ts.y;
        acc[fq*4+2] = td.z + ts.z; acc[fq*4+3] = td.w + ts.w;
    }
    const float* w64 = Wp + 64 * 32 + f0;   // wave-uniform rows
    const float* w65 = Wp + 65 * 32 + f0;
    const float* w66 = Wp + 66 * 32 + f0;
    const float* w67 = Wp + 67 * 32 + f0;
#pragma unroll
    for (int f = 0; f < 8; f++) {
        float a = acc[f];
        a = fmaf(ev.x, w64[f], a);
        a = fmaf(ev.y, w65[f], a);
        a = fmaf(ev.z, w66[f], a);
        a = fmaf(ev.w, w67[f], a);
        acc[f] = fmaxf(a, 0.f);
    }
    float* M = S + OFF_M + e * 36 + f0;
    if (act) {
        *(float4*)(M + 0) = make_float4(acc[0], acc[1], acc[2], acc[3]);
        *(float4*)(M + 4) = make_float4(acc[4], acc[5], acc[6], acc[7]);
    }
}

// ---- PNA aggregation into agg[n][128] = [mean | mn | mx | std]
static __device__ __forceinline__ void agg_phase(float* lds, int nsamp, int tid)
{
    for (int t = tid; t < nsamp * 88; t += TPB) {
        const int s = t / 88, r = t % 88, n = r >> 3, f = (r & 7) * 4;
        float* S = lds + s * SSTRIDE;
        const int e0 = C_INS[n], e1 = C_INS[n + 1];
        float4 sum = make_float4(0.f,0.f,0.f,0.f), sq = make_float4(0.f,0.f,0.f,0.f);
        float4 mn = make_float4(1e30f,1e30f,1e30f,1e30f), mx = make_float4(-1e30f,-1e30f,-1e30f,-1e30f);
        for (int t2 = e0; t2 < e1; t2++) {
            const int e = C_INE[t2];
            float4 mv = *(const float4*)(S + OFF_M + e * 36 + f);
            sum.x += mv.x; sum.y += mv.y; sum.z += mv.z; sum.w += mv.w;
            sq.x = fmaf(mv.x, mv.x, sq.x); sq.y = fmaf(mv.y, mv.y, sq.y);
            sq.z = fmaf(mv.z, mv.z, sq.z); sq.w = fmaf(mv.w, mv.w, sq.w);
            mn.x = fminf(mn.x, mv.x); mn.y = fminf(mn.y, mv.y); mn.z = fminf(mn.z, mv.z); mn.w = fminf(mn.w, mv.w);
            mx.x = fmaxf(mx.x, mv.x); mx.y = fmaxf(mx.y, mv.y); mx.z = fmaxf(mx.z, mv.z); mx.w = fmaxf(mx.w, mv.w);
        }
        const float inv = 1.f / C_CNTC[n];
        float4 mean = make_float4(sum.x*inv, sum.y*inv, sum.z*inv, sum.w*inv);
        float4 msq  = make_float4(sq.x*inv,  sq.y*inv,  sq.z*inv,  sq.w*inv);
        float4 sd;
        sd.x = sqrtf(fmaxf(msq.x - mean.x*mean.x, 0.f) + 1e-5f);
        sd.y = sqrtf(fmaxf(msq.y - mean.y*mean.y, 0.f) + 1e-5f);
        sd.z = sqrtf(fmaxf(msq.z - mean.z*mean.z, 0.f) + 1e-5f);
        sd.w = sqrtf(fmaxf(msq.w - mean.w*mean.w, 0.f) + 1e-5f);
        if (e0 == e1) { mn = make_float4(0.f,0.f,0.f,0.f); mx = make_float4(0.f,0.f,0.f,0.f); }
        float* A = S + OFF_AGG + n * 132;
        *(float4*)(A + 0  + f) = mean;
        *(float4*)(A + 32 + f) = mn;
        *(float4*)(A + 64 + f) = mx;
        *(float4*)(A + 96 + f) = sd;
    }
}

// ---- post1: h1[n][f-quad] = relu(u0 + amp*u1 + att*u2 + b); wave: f0 = w*4
static __device__ __forceinline__ void post1_phase(float* lds, int nsamp, int w, int lane,
                                                   const float* __restrict__ Wp,
                                                   const float* __restrict__ bp)
{
    const int f0 = w * 4;
    const bool act = lane < nsamp * 11;
    const int cidx = act ? lane : 0;
    const int s = cidx / 11, n = cidx % 11;
    const float* A = lds + s * SSTRIDE + OFF_AGG + n * 132;
    const float* W0 = Wp + f0;                  // wave-uniform bases
    const float* W1 = Wp + 128 * 32 + f0;
    const float* W2 = Wp + 256 * 32 + f0;
    float u0[4], u1[4], u2[4];
#pragma unroll
    for (int f = 0; f < 4; f++) { u0[f] = 0.f; u1[f] = 0.f; u2[f] = 0.f; }
    for (int jq = 0; jq < 32; jq++) {
        float4 a4 = *(const float4*)(A + jq * 4);
#pragma unroll
        for (int jj = 0; jj < 4; jj++) {
            float a = (jj == 0) ? a4.x : (jj == 1) ? a4.y : (jj == 2) ? a4.z : a4.w;
            const int j = jq * 4 + jj;
            const float* w0 = W0 + j * 32;
            const float* w1 = W1 + j * 32;
            const float* w2 = W2 + j * 32;
#pragma unroll
            for (int f = 0; f < 4; f++) {
                u0[f] = fmaf(a, w0[f], u0[f]);
                u1[f] = fmaf(a, w1[f], u1[f]);
                u2[f] = fmaf(a, w2[f], u2[f]);
            }
        }
    }
    const float logd = log1pf(C_CNTC[n]);
    const float amp = logd / AVG_LOG;
    const float att = AVG_LOG / logd;
    float* H1 = lds + s * SSTRIDE + OFF_H1 + n * 36 + f0;
    if (act) {
        float o[4];
#pragma unroll
        for (int f = 0; f < 4; f++) {
            float x = u0[f] + amp * u1[f] + att * u2[f] + bp[f0 + f];
            o[f] = fmaxf(x, 0.f);
        }
        *(float4*)(H1) = make_float4(o[0], o[1], o[2], o[3]);
    }
}

// ---- post2 part A: per-wave j-split partials, pre-folded with amp/att (linear)
static __device__ __forceinline__ void post2_partial(float* lds, int nsamp, int w, int lane,
                                                     const float* __restrict__ Wp)
{
    const int j0 = w * 16;
    const bool act = lane < nsamp * 11;
    const int cidx = act ? lane : 0;
    const int s = cidx / 11, n = cidx % 11;
    const float* A = lds + s * SSTRIDE + OFF_AGG + n * 132 + j0;
    float u0 = 0.f, u1 = 0.f, u2 = 0.f;
#pragma unroll
    for (int jq = 0; jq < 4; jq++) {
        float4 a4 = *(const float4*)(A + jq * 4);
#pragma unroll
        for (int jj = 0; jj < 4; jj++) {
            float a = (jj == 0) ? a4.x : (jj == 1) ? a4.y : (jj == 2) ? a4.z : a4.w;
            const int j = j0 + jq * 4 + jj;
            u0 = fmaf(a, Wp[j], u0);
            u1 = fmaf(a, Wp[128 + j], u1);
            u2 = fmaf(a, Wp[256 + j], u2);
        }
    }
    const float logd = log1pf(C_CNTC[n]);
    const float amp = logd / AVG_LOG;
    const float att = AVG_LOG / logd;
    if (act) lds[OFF_PP + w * 55 + lane] = u0 + amp * u1 + att * u2;
}

extern "C" __global__ void __launch_bounds__(TPB, 6)
pna_main(const float* __restrict__ x_input, const float* __restrict__ edge_attr,
         const float* __restrict__ W_emb,  const float* __restrict__ b_emb,
         const float* __restrict__ W_pre1, const float* __restrict__ b_pre1,
         const float* __restrict__ W_post1,const float* __restrict__ b_post1,
         const float* __restrict__ W_pre2, const float* __restrict__ b_pre2,
         const float* __restrict__ W_post2,const float* __restrict__ b_post2,
         float* __restrict__ gacc)
{
    extern __shared__ float lds[];
    const int tid = threadIdx.x;
    const int w = __builtin_amdgcn_readfirstlane(tid >> 6);   // wave id, uniform, 0..7
    const int lane = tid & 63;
    const int s0 = blockIdx.x * SB;
    const int nsamp = min(SB, B_TOT - s0);

    // stage edge_attr
    for (int t = tid; t < nsamp * 68; t += TPB)
        lds[(t / 68) * SSTRIDE + OFF_EA + (t % 68)] = edge_attr[(size_t)s0 * 68 + t];

    // embed directly from global x (L1-broadcast reads): H[n][f] = relu(X[n] @ W_emb[n] + b)
    for (int t = tid; t < nsamp * 352; t += TPB) {
        const int s = t / 352, r = t % 352, n = r >> 5, f = r & 31;
        const float* Xs = x_input + (size_t)(s0 + s) * 44 + n * 4;
        const float* We = W_emb + (n * 4) * 32 + f;
        float v = b_emb[n * 32 + f];
        v = fmaf(Xs[0], We[0],  v);
        v = fmaf(Xs[1], We[32], v);
        v = fmaf(Xs[2], We[64], v);
        v = fmaf(Xs[3], We[96], v);
        lds[s * SSTRIDE + OFF_H + n * 36 + f] = fmaxf(v, 0.f);
    }
    __syncthreads();

    float* pacc = lds + OFF_PACC;

    for (int i = 0; i < 3; i++) {
        if (tid < 11) pacc[tid] = 0.f;
        // conv1
        conv_T(lds, nsamp, w, lane, OFF_H, W_pre1 + i * 68 * 32, b_pre1 + i * 32);
        __syncthreads();
        conv_combine(lds, nsamp, w, lane, W_pre1 + i * 68 * 32);
        __syncthreads();
        agg_phase(lds, nsamp, tid);
        __syncthreads();
        post1_phase(lds, nsamp, w, lane, W_post1 + i * 384 * 32, b_post1 + i * 32);
        __syncthreads();
        // conv2
        conv_T(lds, nsamp, w, lane, OFF_H1, W_pre2 + i * 68 * 32, b_pre2 + i * 32);
        __syncthreads();
        conv_combine(lds, nsamp, w, lane, W_pre2 + i * 68 * 32);
        __syncthreads();
        agg_phase(lds, nsamp, tid);
        __syncthreads();
        post2_partial(lds, nsamp, w, lane, W_post2 + i * 384);
        __syncthreads();
        // reduce partials (wave 0), sigmoid, accumulate
        if (w == 0 && lane < nsamp * 11) {
            const int n = lane % 11;
            float h2 = b_post2[i];
#pragma unroll
            for (int ww = 0; ww < 8; ww++) h2 += lds[OFF_PP + ww * 55 + lane];
            const float p = 1.f / (1.f + expf(-h2));
            atomicAdd(pacc + n, p);
        }
        __syncthreads();
        if (tid < 11) atomicAdd(gacc + i * 11 + tid, pacc[tid]);
        __syncthreads();
    }
}

extern "C" __global__ void pna_zero(float* gacc)
{
    if (threadIdx.x < 33) gacc[threadIdx.x] = 0.f;
}

extern "C" __global__ void pna_final(const float* __restrict__ gacc,
                                     const float* __restrict__ W_fc,
                                     const float* __restrict__ b_fc,
                                     float* __restrict__ out)
{
    const int i = threadIdx.x;
    if (i < 3) {
        float acc = 0.f;
        for (int n = 0; n < 11; n++)
            acc = fmaf(gacc[i * 11 + n] * (1.f / 16384.f), W_fc[i * 11 + n], acc);
        out[i] = acc + b_fc[i];
    }
}

extern "C" void kernel_launch(void* const* d_in, const int* in_sizes, int n_in,
                              void* d_out, int out_size, void* d_ws, size_t ws_size,
                              hipStream_t stream)
{
    (void)in_sizes; (void)n_in; (void)out_size; (void)ws_size;
    const float* x_input   = (const float*)d_in[0];
    const float* edge_attr = (const float*)d_in[1];
    const float* W_emb     = (const float*)d_in[2];
    const float* b_emb     = (const float*)d_in[3];
    const float* W_pre1    = (const float*)d_in[4];
    const float* b_pre1    = (const float*)d_in[5];
    const float* W_post1   = (const float*)d_in[6];
    const float* b_post1   = (const float*)d_in[7];
    const float* W_pre2    = (const float*)d_in[8];
    const float* b_pre2    = (const float*)d_in[9];
    const float* W_post2   = (const float*)d_in[10];
    const float* b_post2   = (const float*)d_in[11];
    const float* W_fc      = (const float*)d_in[12];
    const float* b_fc      = (const float*)d_in[13];
    float* gacc = (float*)d_ws;
    float* out  = (float*)d_out;

    hipLaunchKernelGGL(pna_zero, dim3(1), dim3(64), 0, stream, gacc);
    const int grid = (B_TOT + SB - 1) / SB;
    const size_t shmem = (size_t)LDS_FLOATS * sizeof(float);
    hipLaunchKernelGGL(pna_main, dim3(grid), dim3(TPB), shmem, stream,
                       x_input, edge_attr, W_emb, b_emb,
                       W_pre1, b_pre1, W_post1, b_post1,
                       W_pre2, b_pre2, W_post2, b_post2, gacc);
    hipLaunchKernelGGL(pna_final, dim3(1), dim3(64), 0, stream, gacc, W_fc, b_fc, out);
}